// Round 12
// baseline (119.870 us; speedup 1.0000x reference)
//
#include <hip/hip_runtime.h>
#include <hip/hip_bf16.h>

typedef float  f32x4  __attribute__((ext_vector_type(4)));
typedef __bf16 bf16x8 __attribute__((ext_vector_type(8)));
typedef unsigned int   u32;
typedef unsigned short u16;
typedef u32   u32x2  __attribute__((ext_vector_type(2)));
typedef u32   u32x4  __attribute__((ext_vector_type(4)));
typedef u16   u16x4  __attribute__((ext_vector_type(4)));
typedef u16   u16x8  __attribute__((ext_vector_type(8)));

#define DEV __device__ __forceinline__

constexpr int NB = 8, T = 2048, C = 1024, H = 128;
constexpr int BT = NB * T;

union Frag {
  bf16x8 v;
  u32x4  u4;
  u32x2  u2[2];
  u32    u[4];
  u16    s[8];
};

DEV u16 f2bu(float f) {
  __hip_bfloat16 h = __float2bfloat16(f);
  return __builtin_bit_cast(u16, h);
}
DEV float bu2f(u16 u) {
  return __bfloat162float(__builtin_bit_cast(__hip_bfloat16, u));
}
DEV f32x4 MFMA(bf16x8 a, bf16x8 b, f32x4 c) {
  return __builtin_amdgcn_mfma_f32_16x16x32_bf16(a, b, c, 0, 0, 0);
}

// ---------------------------------------------------------------------------
// Lane-contiguous fragment layouts (16B/lane, 1KB/wave per load):
//   wpq/wpk: [tt8][kc32][hl2][lane64][e8]        (tile-kc stride 1024 u16)
//   wpv:     [tt8][kc32][lane64][e8]             (512)
//   qpk/kpk: [b8][tile128][hs4][hl2][lane64][e8] (tile stride 4096)
//   vpk:     [b8][kt64][ht8][lane64][e8]         (kt stride 4096)
// ---------------------------------------------------------------------------

__global__ void prep_w(const float* __restrict__ Wk, const float* __restrict__ Wq,
                       const float* __restrict__ Wv,
                       u16* __restrict__ wpq, u16* __restrict__ wpk,
                       u16* __restrict__ wpv) {
  const int id = blockIdx.x * 256 + threadIdx.x;   // 24*32*64 = 49152
  if (id >= 24 * 32 * 64) return;
  const int lane = id & 63;
  const int kc   = (id >> 6) & 31;
  const int tile = id >> 11;          // 0..23
  const int mat  = tile >> 3;         // 0=q 1=k 2=v
  const int tt   = tile & 7;
  const int n    = tt * 16 + (lane & 15);
  const float* W = (mat == 0) ? Wq : (mat == 1) ? Wk : Wv;
  u16x8 hi, lo;
  #pragma unroll
  for (int e = 0; e < 8; ++e) {
    const int k = kc * 32 + 4 * (lane >> 4) + (e & 3) + 16 * (e >> 2);
    const float w = W[(size_t)k * H + n];
    u16 h = f2bu(w);
    hi[e] = h;
    lo[e] = f2bu(w - bu2f(h));
  }
  if (mat == 2) {
    *(u16x8*)(wpv + ((size_t)(tt * 32 + kc) * 64 + lane) * 8) = hi;
  } else {
    u16* p = ((mat == 0) ? wpq : wpk) +
             (((size_t)(tt * 32 + kc) * 2 + 0) * 64 + lane) * 8;
    *(u16x8*)p         = hi;
    *(u16x8*)(p + 512) = lo;
  }
}

// ---------------------------------------------------------------------------
// Kernel 1: projections v8 = r11 pipeline with W evicted from LDS.
//  - BM=128, 4 waves, wave owns 2 m-subtiles x 6 n-tiles (2q+2k+2v).
//  - x double-buffered in LDS (36.9 KB only) -> 4 blocks/CU = 4 waves/SIMD.
//  - W fragments loaded per-wave directly from global (lane-contiguous 1KB
//    per instr; W packed = 768 KB, L2-resident; ~655 MB L2 streaming total,
//    hidden by 4-deep block-level overlap).
//  - Single barrier per K-step; x loads for step ks+2 in flight under
//    compute of step ks (r9/r11-proven no-WAR double-buffer pattern).
//  - bid = ng*128 + mt (128%8==0: x-sharers land on same XCD).
// ---------------------------------------------------------------------------
__global__ __launch_bounds__(256, 4) void proj_kernel(
    const float* __restrict__ x,
    const u16* __restrict__ wpq, const u16* __restrict__ wpk,
    const u16* __restrict__ wpv,
    u16* __restrict__ qpk, u16* __restrict__ kpk, u16* __restrict__ vpk) {
  __shared__ u16 xh[2][128][36];       // 18.4 KB
  __shared__ u16 xl[2][128][36];       // 18.4 KB
  const int tid  = threadIdx.x;
  const int ng   = blockIdx.x >> 7;        // 0..3
  const int mt   = blockIdx.x & 127;       // 0..127
  const int m0   = mt * 128;
  const int w    = tid >> 6;               // 0..3
  const int lane = tid & 63;
  const int lg   = lane >> 4, lc = lane & 15;

  // hoisted per-wave W fragment bases (ks-invariant); step offsets applied
  // in compute. planes per jt: q hi/lo (stride 1024/step), k hi/lo, v (512).
  const u16* wq_b[2];
  const u16* wk_b[2];
  const u16* wv_b[2];
  #pragma unroll
  for (int jt = 0; jt < 2; ++jt) {
    wq_b[jt] = wpq + (size_t)((2 * ng + jt) * 32) * 1024 + lane * 8;
    wk_b[jt] = wpk + (size_t)((2 * ng + jt) * 32) * 1024 + lane * 8;
    wv_b[jt] = wpv + (size_t)((2 * ng + jt) * 32) * 512 + lane * 8;
  }

  f32x4 zero = {0.f, 0.f, 0.f, 0.f};
  f32x4 acc[6][2];                         // [j=mat*2+jt][msub]
  #pragma unroll
  for (int j = 0; j < 6; ++j)
    #pragma unroll
    for (int s = 0; s < 2; ++s) acc[j][s] = zero;

  f32x4 xreg[4];

  auto loadX = [&](int ks) {
    const int k = ks > 31 ? 31 : ks;
    #pragma unroll
    for (int j = 0; j < 4; ++j) {
      const int idx = tid + 256 * j;       // 0..1023
      const int row = idx >> 3;
      const int c4  = (idx & 7) * 4;
      xreg[j] = *(const f32x4*)&x[(size_t)(m0 + row) * C + k * 32 + c4];
    }
  };
  auto writeX = [&](int buf) {
    #pragma unroll
    for (int j = 0; j < 4; ++j) {
      const int idx = tid + 256 * j;
      const int row = idx >> 3;
      const int c4  = (idx & 7) * 4;
      u16x4 hv, lv;
      #pragma unroll
      for (int e = 0; e < 4; ++e) {
        u16 h = f2bu(xreg[j][e]);
        hv[e] = h;
        lv[e] = f2bu(xreg[j][e] - bu2f(h));
      }
      *(u16x4*)&xh[buf][row][c4] = hv;
      *(u16x4*)&xl[buf][row][c4] = lv;
    }
  };

  auto compute = [&](int buf, int ks) {
    Frag axh[2], axl[2];
    #pragma unroll
    for (int s = 0; s < 2; ++s) {
      const int row = 32 * w + 16 * s + lc;
      axh[s].u2[0] = *(const u32x2*)&xh[buf][row][4 * lg];
      axh[s].u2[1] = *(const u32x2*)&xh[buf][row][16 + 4 * lg];
      axl[s].u2[0] = *(const u32x2*)&xl[buf][row][4 * lg];
      axl[s].u2[1] = *(const u32x2*)&xl[buf][row][16 + 4 * lg];
    }
    #pragma unroll
    for (int jt = 0; jt < 2; ++jt) {
      // 5 W-fragment global loads (L2-resident), then 14 MFMAs
      Frag qh, ql, kh, kl, vh;
      qh.u4 = *(const u32x4*)(wq_b[jt] + (size_t)ks * 1024);
      ql.u4 = *(const u32x4*)(wq_b[jt] + (size_t)ks * 1024 + 512);
      kh.u4 = *(const u32x4*)(wk_b[jt] + (size_t)ks * 1024);
      kl.u4 = *(const u32x4*)(wk_b[jt] + (size_t)ks * 1024 + 512);
      vh.u4 = *(const u32x4*)(wv_b[jt] + (size_t)ks * 512);
      #pragma unroll
      for (int s = 0; s < 2; ++s) {
        acc[jt][s]     = MFMA(axh[s].v, qh.v, acc[jt][s]);
        acc[jt][s]     = MFMA(axh[s].v, ql.v, acc[jt][s]);
        acc[jt][s]     = MFMA(axl[s].v, qh.v, acc[jt][s]);
        acc[2 + jt][s] = MFMA(axh[s].v, kh.v, acc[2 + jt][s]);
        acc[2 + jt][s] = MFMA(axh[s].v, kl.v, acc[2 + jt][s]);
        acc[2 + jt][s] = MFMA(axl[s].v, kh.v, acc[2 + jt][s]);
        acc[4 + jt][s] = MFMA(axh[s].v, vh.v, acc[4 + jt][s]);
      }
    }
  };

  // prologue: buf0 = step 0; regs = step 1
  loadX(0);
  writeX(0);
  loadX(1);
  __syncthreads();
  int cur = 0;
  for (int ks = 0; ks < 32; ++ks) {
    writeX(cur ^ 1);                 // regs hold step ks+1 -> idle buffer
    loadX(ks + 2);                   // issue step-(ks+2) x loads under compute
    compute(cur, ks);                // 10 W loads + 28 MFMA from buf[cur]
    __syncthreads();                 // single barrier per K-step
    cur ^= 1;
  }

  // Epilogue (r7-verified): value = Out[m0 + 32w + 16s + 4lg + r][(2ng+jt)*16 + lc]
  #pragma unroll
  for (int s = 0; s < 2; ++s) {
    const int tb_abs = mt * 8 + 2 * w + s;
    const int b  = tb_abs >> 7;
    const int tb = tb_abs & 127;
    #pragma unroll
    for (int j = 0; j < 6; ++j) {
      const int mat = j >> 1;
      const int jt  = j & 1;
      const int tt  = 2 * ng + jt;
      #pragma unroll
      for (int r = 0; r < 4; ++r) {
        const float val = acc[j][s][r];
        if (mat < 2) {
          const u16 hvv = f2bu(val);
          const u16 lvv = f2bu(val - bu2f(hvv));
          const int lane_c = 4 * lg + r + 16 * (lc >> 2);
          const int hs = tt >> 1;
          const int e  = (lc & 3) + 4 * (tt & 1);
          u16* dst = ((mat == 0) ? qpk : kpk) +
                     (((size_t)(b * 128 + tb) * 4 + hs) * 2 * 64 + lane_c) * 8 + e;
          dst[0]   = hvv;
          dst[512] = lvv;
        } else {
          const int kt = tb >> 1;
          const int lane_c = lc + 16 * lg;
          const int e = r + 4 * (tb & 1);
          vpk[(((size_t)(b * 64 + kt) * 8 + tt) * 64 + lane_c) * 8 + e] = f2bu(val);
        }
      }
    }
  }
}

// ---------------------------------------------------------------------------
// Kernel 2: causal flash attention (round-4 structure + setprio on MFMA
// clusters). 8 waves, intra-block split-K (kb = w mod 8), 1 q-tile/wave.
// Swapped QK^T so P lands in PV's A-operand layout. LDS combine (bf16).
// ---------------------------------------------------------------------------
__global__ __launch_bounds__(512, 4) void attn_kernel(
    const u16* __restrict__ qpk, const u16* __restrict__ kpk,
    const u16* __restrict__ vpk, float* __restrict__ out) {
  __shared__ float lm[8][16];
  __shared__ float ll[8][16];
  __shared__ u16 lo[8][16][132];     // bf16 partial O

  const int bid = blockIdx.x;
  const int b   = bid & 7;           // batch -> XCD affinity
  const int qt  = bid >> 3;          // 0..127
  const int w    = threadIdx.x >> 6;
  const int lane = threadIdx.x & 63;
  const int lg = lane >> 4, lc = lane & 15;

  // Q fragments: [b][qt][hs][hl][lane][8], tile stride 4096 u16
  Frag bqh[4], bql[4];
  const u16* qp = qpk + (size_t)(b * 128 + qt) * 4096 + lane * 8;
  #pragma unroll
  for (int hs = 0; hs < 4; ++hs) {
    bqh[hs].u4 = *(const u32x4*)(qp + (size_t)(hs * 2 + 0) * 512);
    bql[hs].u4 = *(const u32x4*)(qp + (size_t)(hs * 2 + 1) * 512);
  }

  f32x4 zero = {0.f, 0.f, 0.f, 0.f};
  f32x4 o_acc[8];
  #pragma unroll
  for (int i = 0; i < 8; ++i) o_acc[i] = zero;
  float m_run = -INFINITY, l_run = 0.f;

  const int myq = qt * 16 + lc;
  const int nkb = qt >> 2;           // last 64-wide k-block

  for (int kb = w; kb <= nkb; kb += 8) {
    f32x4 s[4];
    #pragma unroll
    for (int t = 0; t < 4; ++t) s[t] = zero;

    const u16* kp = kpk + (size_t)(b * 128 + kb * 4) * 4096 + lane * 8;
    __builtin_amdgcn_s_setprio(1);
    #pragma unroll
    for (int t = 0; t < 4; ++t) {
      #pragma unroll
      for (int hs = 0; hs < 4; ++hs) {
        const u16* p = kp + (size_t)(t * 8 + hs * 2) * 512;
        Frag akh, akl;
        akh.u4 = *(const u32x4*)p;
        akl.u4 = *(const u32x4*)(p + 512);
        s[t] = MFMA(akh.v, bqh[hs].v, s[t]);
        s[t] = MFMA(akh.v, bql[hs].v, s[t]);
        s[t] = MFMA(akl.v, bqh[hs].v, s[t]);
      }
    }
    __builtin_amdgcn_s_setprio(0);

    // scale by sqrt(C)=32; causal + (tril==0 -> -inf) semantics
    float pmax = -INFINITY;
    #pragma unroll
    for (int t = 0; t < 4; ++t) {
      #pragma unroll
      for (int r = 0; r < 4; ++r) {
        const int kk = kb * 64 + t * 16 + 4 * lg + r;
        float v = s[t][r] * 32.0f;
        if (kk > myq || v == 0.0f) v = -INFINITY;
        s[t][r] = v;
        pmax = fmaxf(pmax, v);
      }
    }
    pmax = fmaxf(pmax, __shfl_xor(pmax, 16));
    pmax = fmaxf(pmax, __shfl_xor(pmax, 32));
    const float m_new = fmaxf(m_run, pmax);
    const float alpha = __expf(m_run - m_new);

    float sum = 0.f;
    u16 pb[16];
    #pragma unroll
    for (int t = 0; t < 4; ++t) {
      #pragma unroll
      for (int r = 0; r < 4; ++r) {
        const float p = __expf(s[t][r] - m_new);
        sum += p;
        pb[t * 4 + r] = f2bu(p);
      }
    }
    sum += __shfl_xor(sum, 16);
    sum += __shfl_xor(sum, 32);
    l_run = l_run * alpha + sum;
    m_run = m_new;

    float al[4];
    #pragma unroll
    for (int r = 0; r < 4; ++r) al[r] = __shfl(alpha, 4 * lg + r);
    #pragma unroll
    for (int i = 0; i < 8; ++i) {
      #pragma unroll
      for (int r = 0; r < 4; ++r) o_acc[i][r] *= al[r];
    }

    Frag pa[2];
    #pragma unroll
    for (int ks = 0; ks < 2; ++ks) {
      #pragma unroll
      for (int e = 0; e < 8; ++e)
        pa[ks].s[e] = pb[(2 * ks + (e >> 2)) * 4 + (e & 3)];
    }

    __builtin_amdgcn_s_setprio(1);
    #pragma unroll
    for (int ks = 0; ks < 2; ++ks) {
      const u16* vp = vpk + (size_t)(b * 64 + kb * 2 + ks) * 4096 + lane * 8;
      #pragma unroll
      for (int ht = 0; ht < 8; ++ht) {
        Frag bv;
        bv.u4 = *(const u32x4*)(vp + (size_t)ht * 512);
        o_acc[ht] = MFMA(pa[ks].v, bv.v, o_acc[ht]);
      }
    }
    __builtin_amdgcn_s_setprio(0);
  }

  // --- combine 8 partials through LDS ---
  if (lane < 16) { lm[w][lane] = m_run; ll[w][lane] = l_run; }
  #pragma unroll
  for (int ht = 0; ht < 8; ++ht)
    #pragma unroll
    for (int r = 0; r < 4; ++r)
      lo[w][4 * lg + r][ht * 16 + lc] = f2bu(o_acc[ht][r]);
  __syncthreads();

  const int tid = threadIdx.x;
  const int q  = tid >> 5;            // 0..15
  const int hb = (tid & 31) * 4;      // 0..124
  float M = -INFINITY;
  #pragma unroll
  for (int ww = 0; ww < 8; ++ww) M = fmaxf(M, lm[ww][q]);
  float lsum = 0.f;
  f32x4 osum = {0.f, 0.f, 0.f, 0.f};
  #pragma unroll
  for (int ww = 0; ww < 8; ++ww) {
    const float sc = __expf(lm[ww][q] - M);
    lsum += sc * ll[ww][q];
    const u16x4 ov = *(const u16x4*)&lo[ww][q][hb];
    #pragma unroll
    for (int j = 0; j < 4; ++j) osum[j] += sc * bu2f(ov[j]);
  }
  const float inv = 1.0f / lsum;
  f32x4 res = {osum[0] * inv, osum[1] * inv, osum[2] * inv, osum[3] * inv};
  *(f32x4*)&out[((size_t)(b * T + qt * 16 + q)) * H + hb] = res;
}

// ---------------------------------------------------------------------------
extern "C" void kernel_launch(void* const* d_in, const int* in_sizes, int n_in,
                              void* d_out, int out_size, void* d_ws, size_t ws_size,
                              hipStream_t stream) {
  (void)in_sizes; (void)n_in; (void)out_size; (void)ws_size;
  const float* x  = (const float*)d_in[0];
  const float* Wk = (const float*)d_in[1];
  const float* Wq = (const float*)d_in[2];
  const float* Wv = (const float*)d_in[3];
  float* out = (float*)d_out;

  u16* w = (u16*)d_ws;
  const size_t WPQK = (size_t)8 * 32 * 2 * 64 * 8;       // 262144
  const size_t WPV  = (size_t)8 * 32 * 64 * 8;           // 131072
  const size_t QKP  = (size_t)NB * 128 * 4 * 2 * 64 * 8; // 4194304
  u16* wpq = w;
  u16* wpk = wpq + WPQK;
  u16* wpv = wpk + WPQK;
  u16* qpk = wpv + WPV;
  u16* kpk = qpk + QKP;
  u16* vpk = kpk + QKP;

  prep_w<<<192, 256, 0, stream>>>(Wk, Wq, Wv, wpq, wpk, wpv);
  proj_kernel<<<512, 256, 0, stream>>>(x, wpq, wpk, wpv, qpk, kpk, vpk);
  attn_kernel<<<NB * (T / 16), 512, 0, stream>>>(qpk, kpk, vpk, out);
}

// Round 13
// 99.543 us; speedup vs baseline: 1.2042x; 1.2042x over previous
//
#include <hip/hip_runtime.h>
#include <hip/hip_bf16.h>

typedef float  f32x4  __attribute__((ext_vector_type(4)));
typedef __bf16 bf16x8 __attribute__((ext_vector_type(8)));
typedef unsigned int   u32;
typedef unsigned short u16;
typedef u32   u32x2  __attribute__((ext_vector_type(2)));
typedef u32   u32x4  __attribute__((ext_vector_type(4)));
typedef u16   u16x4  __attribute__((ext_vector_type(4)));
typedef u16   u16x8  __attribute__((ext_vector_type(8)));

#define DEV __device__ __forceinline__

constexpr int NB = 8, T = 2048, C = 1024, H = 128;
constexpr int BT = NB * T;

union Frag {
  bf16x8 v;
  u32x4  u4;
  u32x2  u2[2];
  u32    u[4];
  u16    s[8];
};

DEV u16 f2bu(float f) {
  __hip_bfloat16 h = __float2bfloat16(f);
  return __builtin_bit_cast(u16, h);
}
DEV float bu2f(u16 u) {
  return __bfloat162float(__builtin_bit_cast(__hip_bfloat16, u));
}
DEV f32x4 MFMA(bf16x8 a, bf16x8 b, f32x4 c) {
  return __builtin_amdgcn_mfma_f32_16x16x32_bf16(a, b, c, 0, 0, 0);
}

// ---------------------------------------------------------------------------
// Lane-contiguous fragment layouts (16B/lane, 1KB/wave per load):
//   wpq/wpk: [tt8][kc32][hl2][lane64][e8]        (tile-kc stride 1024 u16)
//   wpv:     [tt8][kc32][lane64][e8]             (512)
//   qpk/kpk: [b8][tile128][hs4][hl2][lane64][e8] (tile stride 4096)
//   vpk:     [b8][kt64][ht8][lane64][e8]         (kt stride 4096)
// ---------------------------------------------------------------------------

__global__ void prep_w(const float* __restrict__ Wk, const float* __restrict__ Wq,
                       const float* __restrict__ Wv,
                       u16* __restrict__ wpq, u16* __restrict__ wpk,
                       u16* __restrict__ wpv) {
  const int id = blockIdx.x * 256 + threadIdx.x;   // 24*32*64 = 49152
  if (id >= 24 * 32 * 64) return;
  const int lane = id & 63;
  const int kc   = (id >> 6) & 31;
  const int tile = id >> 11;          // 0..23
  const int mat  = tile >> 3;         // 0=q 1=k 2=v
  const int tt   = tile & 7;
  const int n    = tt * 16 + (lane & 15);
  const float* W = (mat == 0) ? Wq : (mat == 1) ? Wk : Wv;
  u16x8 hi, lo;
  #pragma unroll
  for (int e = 0; e < 8; ++e) {
    const int k = kc * 32 + 4 * (lane >> 4) + (e & 3) + 16 * (e >> 2);
    const float w = W[(size_t)k * H + n];
    u16 h = f2bu(w);
    hi[e] = h;
    lo[e] = f2bu(w - bu2f(h));
  }
  if (mat == 2) {
    *(u16x8*)(wpv + ((size_t)(tt * 32 + kc) * 64 + lane) * 8) = hi;
  } else {
    u16* p = ((mat == 0) ? wpq : wpk) +
             (((size_t)(tt * 32 + kc) * 2 + 0) * 64 + lane) * 8;
    *(u16x8*)p         = hi;
    *(u16x8*)(p + 512) = lo;
  }
}

// ---------------------------------------------------------------------------
// Kernel 1: projections v9 = r11 dataflow with 8-wave (512-thread) blocks.
//  - Wave = (ms = w&3 -> rows 32ms..32ms+31, nh = w>>2 -> 1 q + 1 k + 1 v
//    tile of n-group ng). Same LDS layout/pipeline as r11 (proven 60 us),
//    but 2 blocks/CU x 8 waves = 16 waves/CU (2x latency hiding) and
//    halved per-thread staging + acc VGPR.
//  - x + W double-buffered in LDS; global loads for step ks+2 issued during
//    step ks; single barrier per K-step.
//  - bid = ng*128 + mt (128%8==0: x-sharers land on same XCD).
// ---------------------------------------------------------------------------
__global__ __launch_bounds__(512, 4) void proj_kernel(
    const float* __restrict__ x,
    const u16* __restrict__ wpq, const u16* __restrict__ wpk,
    const u16* __restrict__ wpv,
    u16* __restrict__ qpk, u16* __restrict__ kpk, u16* __restrict__ vpk) {
  __shared__ u16 xh[2][128][36];       // 18.4 KB
  __shared__ u16 xl[2][128][36];       // 18.4 KB
  __shared__ u16 wsl[2][640 * 8];      // 20.5 KB: [plane10][lane64][e8]
  const int tid  = threadIdx.x;            // 0..511
  const int ng   = blockIdx.x >> 7;        // 0..3
  const int mt   = blockIdx.x & 127;       // 0..127
  const int m0   = mt * 128;
  const int w    = tid >> 6;               // 0..7
  const int lane = tid & 63;
  const int lg   = lane >> 4, lc = lane & 15;
  const int ms   = w & 3;                  // rows 32ms..32ms+31
  const int nh   = w >> 2;                 // n-half: tile tt = 2ng+nh

  // ---- hoisted W staging coords: 640 chunks = 10 planes x 64 lanes;
  // planes: 0-3 q(jt,hl), 4-7 k(jt,hl), 8-9 v(jt). 2 rounds of 512 threads.
  const u16* wbase[2];
  int wstep[2], wofs[2];
  bool wact[2];
  #pragma unroll
  for (int i = 0; i < 2; ++i) {
    const int c = tid + 512 * i;
    wact[i] = (c < 640);
    const int cc = wact[i] ? c : 0;
    const int p  = cc >> 6;
    const int ln = cc & 63;
    const u16* base;
    int stride;
    if (p < 4) {
      base = wpq + (size_t)((2 * ng + (p >> 1)) * 32) * 1024 + (p & 1) * 512 + ln * 8;
      stride = 1024;
    } else if (p < 8) {
      base = wpk + (size_t)((2 * ng + ((p - 4) >> 1)) * 32) * 1024 + ((p - 4) & 1) * 512 + ln * 8;
      stride = 1024;
    } else {
      base = wpv + (size_t)((2 * ng + (p - 8)) * 32) * 512 + ln * 8;
      stride = 512;
    }
    wbase[i] = base;
    wstep[i] = stride;
    wofs[i]  = (p * 64 + ln) * 8;
  }

  f32x4 zero = {0.f, 0.f, 0.f, 0.f};
  f32x4 acc[3][2];                         // [mat q,k,v][msub]
  #pragma unroll
  for (int j = 0; j < 3; ++j)
    #pragma unroll
    for (int s = 0; s < 2; ++s) acc[j][s] = zero;

  f32x4 xreg[2];
  u16x8 wreg[2];

  auto loadX = [&](int ks) {
    const int k = ks > 31 ? 31 : ks;
    #pragma unroll
    for (int j = 0; j < 2; ++j) {
      const int idx = tid + 512 * j;       // 0..1023
      const int row = idx >> 3;
      const int c4  = (idx & 7) * 4;
      xreg[j] = *(const f32x4*)&x[(size_t)(m0 + row) * C + k * 32 + c4];
    }
  };
  auto writeX = [&](int buf) {
    #pragma unroll
    for (int j = 0; j < 2; ++j) {
      const int idx = tid + 512 * j;
      const int row = idx >> 3;
      const int c4  = (idx & 7) * 4;
      u16x4 hv, lv;
      #pragma unroll
      for (int e = 0; e < 4; ++e) {
        u16 h = f2bu(xreg[j][e]);
        hv[e] = h;
        lv[e] = f2bu(xreg[j][e] - bu2f(h));
      }
      *(u16x4*)&xh[buf][row][c4] = hv;
      *(u16x4*)&xl[buf][row][c4] = lv;
    }
  };
  auto loadW = [&](int ks) {
    const int k = ks > 31 ? 31 : ks;
    #pragma unroll
    for (int i = 0; i < 2; ++i)
      if (wact[i]) wreg[i] = *(const u16x8*)(wbase[i] + (size_t)k * wstep[i]);
  };
  auto writeW = [&](int buf) {
    #pragma unroll
    for (int i = 0; i < 2; ++i)
      if (wact[i]) *(u16x8*)&wsl[buf][wofs[i]] = wreg[i];
  };

  auto compute = [&](int buf) {
    Frag axh[2], axl[2];
    #pragma unroll
    for (int s = 0; s < 2; ++s) {
      const int row = 32 * ms + 16 * s + lc;
      axh[s].u2[0] = *(const u32x2*)&xh[buf][row][4 * lg];
      axh[s].u2[1] = *(const u32x2*)&xh[buf][row][16 + 4 * lg];
      axl[s].u2[0] = *(const u32x2*)&xl[buf][row][4 * lg];
      axl[s].u2[1] = *(const u32x2*)&xl[buf][row][16 + 4 * lg];
    }
    Frag qh, ql, kh, kl, vh;
    qh.u4 = *(const u32x4*)&wsl[buf][((0 + nh * 2 + 0) * 64 + lane) * 8];
    ql.u4 = *(const u32x4*)&wsl[buf][((0 + nh * 2 + 1) * 64 + lane) * 8];
    kh.u4 = *(const u32x4*)&wsl[buf][((4 + nh * 2 + 0) * 64 + lane) * 8];
    kl.u4 = *(const u32x4*)&wsl[buf][((4 + nh * 2 + 1) * 64 + lane) * 8];
    vh.u4 = *(const u32x4*)&wsl[buf][((8 + nh) * 64 + lane) * 8];
    #pragma unroll
    for (int s = 0; s < 2; ++s) {
      acc[0][s] = MFMA(axh[s].v, qh.v, acc[0][s]);
      acc[0][s] = MFMA(axh[s].v, ql.v, acc[0][s]);
      acc[0][s] = MFMA(axl[s].v, qh.v, acc[0][s]);
      acc[1][s] = MFMA(axh[s].v, kh.v, acc[1][s]);
      acc[1][s] = MFMA(axh[s].v, kl.v, acc[1][s]);
      acc[1][s] = MFMA(axl[s].v, kh.v, acc[1][s]);
      acc[2][s] = MFMA(axh[s].v, vh.v, acc[2][s]);
    }
  };

  // prologue: buf0 = step 0; regs = step 1
  loadX(0); loadW(0);
  writeX(0); writeW(0);
  loadX(1); loadW(1);
  __syncthreads();
  int cur = 0;
  for (int ks = 0; ks < 32; ++ks) {
    writeX(cur ^ 1);                 // regs hold step ks+1 -> idle buffer
    writeW(cur ^ 1);
    loadX(ks + 2);                   // issue step-(ks+2) loads under compute
    loadW(ks + 2);
    compute(cur);                    // 14 MFMA from buf[cur]
    __syncthreads();                 // single barrier per K-step
    cur ^= 1;
  }

  // Epilogue (r7-verified formulas): value = Out[m0+32ms+16s+4lg+r][tt*16+lc]
  const int tt = 2 * ng + nh;
  #pragma unroll
  for (int s = 0; s < 2; ++s) {
    const int tb_abs = mt * 8 + 2 * ms + s;
    const int b  = tb_abs >> 7;
    const int tb = tb_abs & 127;
    const int hs = tt >> 1;
    const int e  = (lc & 3) + 4 * (tt & 1);
    #pragma unroll
    for (int r = 0; r < 4; ++r) {
      const int lane_c = 4 * lg + r + 16 * (lc >> 2);
      // q
      {
        const float val = acc[0][s][r];
        const u16 hvv = f2bu(val);
        u16* dst = qpk + (((size_t)(b * 128 + tb) * 4 + hs) * 2 * 64 + lane_c) * 8 + e;
        dst[0]   = hvv;
        dst[512] = f2bu(val - bu2f(hvv));
      }
      // k
      {
        const float val = acc[1][s][r];
        const u16 hvv = f2bu(val);
        u16* dst = kpk + (((size_t)(b * 128 + tb) * 4 + hs) * 2 * 64 + lane_c) * 8 + e;
        dst[0]   = hvv;
        dst[512] = f2bu(val - bu2f(hvv));
      }
      // v
      {
        const int kt = tb >> 1;
        const int lane_cv = lc + 16 * lg;
        const int ev = r + 4 * (tb & 1);
        vpk[(((size_t)(b * 64 + kt) * 8 + tt) * 64 + lane_cv) * 8 + ev] = f2bu(acc[2][s][r]);
      }
    }
  }
}

// ---------------------------------------------------------------------------
// Kernel 2: causal flash attention (round-4 structure + setprio on MFMA
// clusters). 8 waves, intra-block split-K (kb = w mod 8), 1 q-tile/wave.
// Swapped QK^T so P lands in PV's A-operand layout. LDS combine (bf16).
// ---------------------------------------------------------------------------
__global__ __launch_bounds__(512, 4) void attn_kernel(
    const u16* __restrict__ qpk, const u16* __restrict__ kpk,
    const u16* __restrict__ vpk, float* __restrict__ out) {
  __shared__ float lm[8][16];
  __shared__ float ll[8][16];
  __shared__ u16 lo[8][16][132];     // bf16 partial O

  const int bid = blockIdx.x;
  const int b   = bid & 7;           // batch -> XCD affinity
  const int qt  = bid >> 3;          // 0..127
  const int w    = threadIdx.x >> 6;
  const int lane = threadIdx.x & 63;
  const int lg = lane >> 4, lc = lane & 15;

  // Q fragments: [b][qt][hs][hl][lane][8], tile stride 4096 u16
  Frag bqh[4], bql[4];
  const u16* qp = qpk + (size_t)(b * 128 + qt) * 4096 + lane * 8;
  #pragma unroll
  for (int hs = 0; hs < 4; ++hs) {
    bqh[hs].u4 = *(const u32x4*)(qp + (size_t)(hs * 2 + 0) * 512);
    bql[hs].u4 = *(const u32x4*)(qp + (size_t)(hs * 2 + 1) * 512);
  }

  f32x4 zero = {0.f, 0.f, 0.f, 0.f};
  f32x4 o_acc[8];
  #pragma unroll
  for (int i = 0; i < 8; ++i) o_acc[i] = zero;
  float m_run = -INFINITY, l_run = 0.f;

  const int myq = qt * 16 + lc;
  const int nkb = qt >> 2;           // last 64-wide k-block

  for (int kb = w; kb <= nkb; kb += 8) {
    f32x4 s[4];
    #pragma unroll
    for (int t = 0; t < 4; ++t) s[t] = zero;

    const u16* kp = kpk + (size_t)(b * 128 + kb * 4) * 4096 + lane * 8;
    __builtin_amdgcn_s_setprio(1);
    #pragma unroll
    for (int t = 0; t < 4; ++t) {
      #pragma unroll
      for (int hs = 0; hs < 4; ++hs) {
        const u16* p = kp + (size_t)(t * 8 + hs * 2) * 512;
        Frag akh, akl;
        akh.u4 = *(const u32x4*)p;
        akl.u4 = *(const u32x4*)(p + 512);
        s[t] = MFMA(akh.v, bqh[hs].v, s[t]);
        s[t] = MFMA(akh.v, bql[hs].v, s[t]);
        s[t] = MFMA(akl.v, bqh[hs].v, s[t]);
      }
    }
    __builtin_amdgcn_s_setprio(0);

    // scale by sqrt(C)=32; causal + (tril==0 -> -inf) semantics
    float pmax = -INFINITY;
    #pragma unroll
    for (int t = 0; t < 4; ++t) {
      #pragma unroll
      for (int r = 0; r < 4; ++r) {
        const int kk = kb * 64 + t * 16 + 4 * lg + r;
        float v = s[t][r] * 32.0f;
        if (kk > myq || v == 0.0f) v = -INFINITY;
        s[t][r] = v;
        pmax = fmaxf(pmax, v);
      }
    }
    pmax = fmaxf(pmax, __shfl_xor(pmax, 16));
    pmax = fmaxf(pmax, __shfl_xor(pmax, 32));
    const float m_new = fmaxf(m_run, pmax);
    const float alpha = __expf(m_run - m_new);

    float sum = 0.f;
    u16 pb[16];
    #pragma unroll
    for (int t = 0; t < 4; ++t) {
      #pragma unroll
      for (int r = 0; r < 4; ++r) {
        const float p = __expf(s[t][r] - m_new);
        sum += p;
        pb[t * 4 + r] = f2bu(p);
      }
    }
    sum += __shfl_xor(sum, 16);
    sum += __shfl_xor(sum, 32);
    l_run = l_run * alpha + sum;
    m_run = m_new;

    float al[4];
    #pragma unroll
    for (int r = 0; r < 4; ++r) al[r] = __shfl(alpha, 4 * lg + r);
    #pragma unroll
    for (int i = 0; i < 8; ++i) {
      #pragma unroll
      for (int r = 0; r < 4; ++r) o_acc[i][r] *= al[r];
    }

    Frag pa[2];
    #pragma unroll
    for (int ks = 0; ks < 2; ++ks) {
      #pragma unroll
      for (int e = 0; e < 8; ++e)
        pa[ks].s[e] = pb[(2 * ks + (e >> 2)) * 4 + (e & 3)];
    }

    __builtin_amdgcn_s_setprio(1);
    #pragma unroll
    for (int ks = 0; ks < 2; ++ks) {
      const u16* vp = vpk + (size_t)(b * 64 + kb * 2 + ks) * 4096 + lane * 8;
      #pragma unroll
      for (int ht = 0; ht < 8; ++ht) {
        Frag bv;
        bv.u4 = *(const u32x4*)(vp + (size_t)ht * 512);
        o_acc[ht] = MFMA(pa[ks].v, bv.v, o_acc[ht]);
      }
    }
    __builtin_amdgcn_s_setprio(0);
  }

  // --- combine 8 partials through LDS ---
  if (lane < 16) { lm[w][lane] = m_run; ll[w][lane] = l_run; }
  #pragma unroll
  for (int ht = 0; ht < 8; ++ht)
    #pragma unroll
    for (int r = 0; r < 4; ++r)
      lo[w][4 * lg + r][ht * 16 + lc] = f2bu(o_acc[ht][r]);
  __syncthreads();

  const int tid = threadIdx.x;
  const int q  = tid >> 5;            // 0..15
  const int hb = (tid & 31) * 4;      // 0..124
  float M = -INFINITY;
  #pragma unroll
  for (int ww = 0; ww < 8; ++ww) M = fmaxf(M, lm[ww][q]);
  float lsum = 0.f;
  f32x4 osum = {0.f, 0.f, 0.f, 0.f};
  #pragma unroll
  for (int ww = 0; ww < 8; ++ww) {
    const float sc = __expf(lm[ww][q] - M);
    lsum += sc * ll[ww][q];
    const u16x4 ov = *(const u16x4*)&lo[ww][q][hb];
    #pragma unroll
    for (int j = 0; j < 4; ++j) osum[j] += sc * bu2f(ov[j]);
  }
  const float inv = 1.0f / lsum;
  f32x4 res = {osum[0] * inv, osum[1] * inv, osum[2] * inv, osum[3] * inv};
  *(f32x4*)&out[((size_t)(b * T + qt * 16 + q)) * H + hb] = res;
}

// ---------------------------------------------------------------------------
extern "C" void kernel_launch(void* const* d_in, const int* in_sizes, int n_in,
                              void* d_out, int out_size, void* d_ws, size_t ws_size,
                              hipStream_t stream) {
  (void)in_sizes; (void)n_in; (void)out_size; (void)ws_size;
  const float* x  = (const float*)d_in[0];
  const float* Wk = (const float*)d_in[1];
  const float* Wq = (const float*)d_in[2];
  const float* Wv = (const float*)d_in[3];
  float* out = (float*)d_out;

  u16* w = (u16*)d_ws;
  const size_t WPQK = (size_t)8 * 32 * 2 * 64 * 8;       // 262144
  const size_t WPV  = (size_t)8 * 32 * 64 * 8;           // 131072
  const size_t QKP  = (size_t)NB * 128 * 4 * 2 * 64 * 8; // 4194304
  u16* wpq = w;
  u16* wpk = wpq + WPQK;
  u16* wpv = wpk + WPQK;
  u16* qpk = wpv + WPV;
  u16* kpk = qpk + QKP;
  u16* vpk = kpk + QKP;

  prep_w<<<192, 256, 0, stream>>>(Wk, Wq, Wv, wpq, wpk, wpv);
  proj_kernel<<<512, 512, 0, stream>>>(x, wpq, wpk, wpv, qpk, kpk, vpk);
  attn_kernel<<<NB * (T / 16), 512, 0, stream>>>(qpk, kpk, vpk, out);
}

// Round 14
// 99.263 us; speedup vs baseline: 1.2076x; 1.0028x over previous
//
#include <hip/hip_runtime.h>
#include <hip/hip_bf16.h>

typedef float  f32x4  __attribute__((ext_vector_type(4)));
typedef __bf16 bf16x8 __attribute__((ext_vector_type(8)));
typedef unsigned int   u32;
typedef unsigned short u16;
typedef u32   u32x2  __attribute__((ext_vector_type(2)));
typedef u32   u32x4  __attribute__((ext_vector_type(4)));
typedef u16   u16x4  __attribute__((ext_vector_type(4)));
typedef u16   u16x8  __attribute__((ext_vector_type(8)));

#define DEV __device__ __forceinline__

constexpr int NB = 8, T = 2048, C = 1024, H = 128;
constexpr int BT = NB * T;

union Frag {
  bf16x8 v;
  u32x4  u4;
  u32x2  u2[2];
  u32    u[4];
  u16    s[8];
};

DEV u16 f2bu(float f) {
  __hip_bfloat16 h = __float2bfloat16(f);
  return __builtin_bit_cast(u16, h);
}
DEV float bu2f(u16 u) {
  return __bfloat162float(__builtin_bit_cast(__hip_bfloat16, u));
}
DEV f32x4 MFMA(bf16x8 a, bf16x8 b, f32x4 c) {
  return __builtin_amdgcn_mfma_f32_16x16x32_bf16(a, b, c, 0, 0, 0);
}

// Barrier WITHOUT the vmcnt(0) drain __syncthreads would emit: LDS ops must
// be complete (lgkmcnt(0)) for cross-wave visibility, but global loads feed
// REGISTERS here — the compiler's counted vmcnt before their use suffices.
// Loads stay in flight across the barrier (T4 mechanism).
DEV void bar_lds_only() {
  asm volatile("s_waitcnt lgkmcnt(0)" ::: "memory");
  __builtin_amdgcn_s_barrier();
  __builtin_amdgcn_sched_barrier(0);
}

// ---------------------------------------------------------------------------
// Lane-contiguous fragment layouts (16B/lane, 1KB/wave per load):
//   wpq/wpk: [tt8][kc32][hl2][lane64][e8]        (tile-kc stride 1024 u16)
//   wpv:     [tt8][kc32][lane64][e8]             (512)
//   qpk/kpk: [b8][tile128][hs4][hl2][lane64][e8] (tile stride 4096)
//   vpk:     [b8][kt64][ht8][lane64][e8]         (kt stride 4096)
// ---------------------------------------------------------------------------

__global__ void prep_w(const float* __restrict__ Wk, const float* __restrict__ Wq,
                       const float* __restrict__ Wv,
                       u16* __restrict__ wpq, u16* __restrict__ wpk,
                       u16* __restrict__ wpv) {
  const int id = blockIdx.x * 256 + threadIdx.x;   // 24*32*64 = 49152
  if (id >= 24 * 32 * 64) return;
  const int lane = id & 63;
  const int kc   = (id >> 6) & 31;
  const int tile = id >> 11;          // 0..23
  const int mat  = tile >> 3;         // 0=q 1=k 2=v
  const int tt   = tile & 7;
  const int n    = tt * 16 + (lane & 15);
  const float* W = (mat == 0) ? Wq : (mat == 1) ? Wk : Wv;
  u16x8 hi, lo;
  #pragma unroll
  for (int e = 0; e < 8; ++e) {
    const int k = kc * 32 + 4 * (lane >> 4) + (e & 3) + 16 * (e >> 2);
    const float w = W[(size_t)k * H + n];
    u16 h = f2bu(w);
    hi[e] = h;
    lo[e] = f2bu(w - bu2f(h));
  }
  if (mat == 2) {
    *(u16x8*)(wpv + ((size_t)(tt * 32 + kc) * 64 + lane) * 8) = hi;
  } else {
    u16* p = ((mat == 0) ? wpq : wpk) +
             (((size_t)(tt * 32 + kc) * 2 + 0) * 64 + lane) * 8;
    *(u16x8*)p         = hi;
    *(u16x8*)(p + 512) = lo;
  }
}

// ---------------------------------------------------------------------------
// Kernel 1: projections v10 = r13 (8-wave, double-buffer, single barrier)
// with the vmcnt-drain-free barrier. Everything else identical to r13.
// ---------------------------------------------------------------------------
__global__ __launch_bounds__(512, 4) void proj_kernel(
    const float* __restrict__ x,
    const u16* __restrict__ wpq, const u16* __restrict__ wpk,
    const u16* __restrict__ wpv,
    u16* __restrict__ qpk, u16* __restrict__ kpk, u16* __restrict__ vpk) {
  __shared__ u16 xh[2][128][36];       // 18.4 KB
  __shared__ u16 xl[2][128][36];       // 18.4 KB
  __shared__ u16 wsl[2][640 * 8];      // 20.5 KB: [plane10][lane64][e8]
  const int tid  = threadIdx.x;            // 0..511
  const int ng   = blockIdx.x >> 7;        // 0..3
  const int mt   = blockIdx.x & 127;       // 0..127
  const int m0   = mt * 128;
  const int w    = tid >> 6;               // 0..7
  const int lane = tid & 63;
  const int lg   = lane >> 4, lc = lane & 15;
  const int ms   = w & 3;                  // rows 32ms..32ms+31
  const int nh   = w >> 2;                 // n-half: tile tt = 2ng+nh

  // ---- hoisted W staging coords: 640 chunks = 10 planes x 64 lanes;
  // planes: 0-3 q(jt,hl), 4-7 k(jt,hl), 8-9 v(jt). 2 rounds of 512 threads.
  const u16* wbase[2];
  int wstep[2], wofs[2];
  bool wact[2];
  #pragma unroll
  for (int i = 0; i < 2; ++i) {
    const int c = tid + 512 * i;
    wact[i] = (c < 640);
    const int cc = wact[i] ? c : 0;
    const int p  = cc >> 6;
    const int ln = cc & 63;
    const u16* base;
    int stride;
    if (p < 4) {
      base = wpq + (size_t)((2 * ng + (p >> 1)) * 32) * 1024 + (p & 1) * 512 + ln * 8;
      stride = 1024;
    } else if (p < 8) {
      base = wpk + (size_t)((2 * ng + ((p - 4) >> 1)) * 32) * 1024 + ((p - 4) & 1) * 512 + ln * 8;
      stride = 1024;
    } else {
      base = wpv + (size_t)((2 * ng + (p - 8)) * 32) * 512 + ln * 8;
      stride = 512;
    }
    wbase[i] = base;
    wstep[i] = stride;
    wofs[i]  = (p * 64 + ln) * 8;
  }

  f32x4 zero = {0.f, 0.f, 0.f, 0.f};
  f32x4 acc[3][2];                         // [mat q,k,v][msub]
  #pragma unroll
  for (int j = 0; j < 3; ++j)
    #pragma unroll
    for (int s = 0; s < 2; ++s) acc[j][s] = zero;

  f32x4 xreg[2];
  u16x8 wreg[2];

  auto loadX = [&](int ks) {
    const int k = ks > 31 ? 31 : ks;
    #pragma unroll
    for (int j = 0; j < 2; ++j) {
      const int idx = tid + 512 * j;       // 0..1023
      const int row = idx >> 3;
      const int c4  = (idx & 7) * 4;
      xreg[j] = *(const f32x4*)&x[(size_t)(m0 + row) * C + k * 32 + c4];
    }
  };
  auto writeX = [&](int buf) {
    #pragma unroll
    for (int j = 0; j < 2; ++j) {
      const int idx = tid + 512 * j;
      const int row = idx >> 3;
      const int c4  = (idx & 7) * 4;
      u16x4 hv, lv;
      #pragma unroll
      for (int e = 0; e < 4; ++e) {
        u16 h = f2bu(xreg[j][e]);
        hv[e] = h;
        lv[e] = f2bu(xreg[j][e] - bu2f(h));
      }
      *(u16x4*)&xh[buf][row][c4] = hv;
      *(u16x4*)&xl[buf][row][c4] = lv;
    }
  };
  auto loadW = [&](int ks) {
    const int k = ks > 31 ? 31 : ks;
    #pragma unroll
    for (int i = 0; i < 2; ++i)
      if (wact[i]) wreg[i] = *(const u16x8*)(wbase[i] + (size_t)k * wstep[i]);
  };
  auto writeW = [&](int buf) {
    #pragma unroll
    for (int i = 0; i < 2; ++i)
      if (wact[i]) *(u16x8*)&wsl[buf][wofs[i]] = wreg[i];
  };

  auto compute = [&](int buf) {
    Frag axh[2], axl[2];
    #pragma unroll
    for (int s = 0; s < 2; ++s) {
      const int row = 32 * ms + 16 * s + lc;
      axh[s].u2[0] = *(const u32x2*)&xh[buf][row][4 * lg];
      axh[s].u2[1] = *(const u32x2*)&xh[buf][row][16 + 4 * lg];
      axl[s].u2[0] = *(const u32x2*)&xl[buf][row][4 * lg];
      axl[s].u2[1] = *(const u32x2*)&xl[buf][row][16 + 4 * lg];
    }
    Frag qh, ql, kh, kl, vh;
    qh.u4 = *(const u32x4*)&wsl[buf][((0 + nh * 2 + 0) * 64 + lane) * 8];
    ql.u4 = *(const u32x4*)&wsl[buf][((0 + nh * 2 + 1) * 64 + lane) * 8];
    kh.u4 = *(const u32x4*)&wsl[buf][((4 + nh * 2 + 0) * 64 + lane) * 8];
    kl.u4 = *(const u32x4*)&wsl[buf][((4 + nh * 2 + 1) * 64 + lane) * 8];
    vh.u4 = *(const u32x4*)&wsl[buf][((8 + nh) * 64 + lane) * 8];
    #pragma unroll
    for (int s = 0; s < 2; ++s) {
      acc[0][s] = MFMA(axh[s].v, qh.v, acc[0][s]);
      acc[0][s] = MFMA(axh[s].v, ql.v, acc[0][s]);
      acc[0][s] = MFMA(axl[s].v, qh.v, acc[0][s]);
      acc[1][s] = MFMA(axh[s].v, kh.v, acc[1][s]);
      acc[1][s] = MFMA(axh[s].v, kl.v, acc[1][s]);
      acc[1][s] = MFMA(axl[s].v, kh.v, acc[1][s]);
      acc[2][s] = MFMA(axh[s].v, vh.v, acc[2][s]);
    }
  };

  // prologue: buf0 = step 0; regs = step 1
  loadX(0); loadW(0);
  writeX(0); writeW(0);
  loadX(1); loadW(1);
  bar_lds_only();
  int cur = 0;
  for (int ks = 0; ks < 32; ++ks) {
    writeX(cur ^ 1);                 // regs hold step ks+1 -> idle buffer
    writeW(cur ^ 1);
    loadX(ks + 2);                   // loads stay in flight ACROSS the barrier
    loadW(ks + 2);
    compute(cur);                    // 14 MFMA from buf[cur]
    bar_lds_only();                  // lgkmcnt(0) + s_barrier, NO vmcnt drain
    cur ^= 1;
  }

  // Epilogue (r7-verified formulas): value = Out[m0+32ms+16s+4lg+r][tt*16+lc]
  const int tt = 2 * ng + nh;
  #pragma unroll
  for (int s = 0; s < 2; ++s) {
    const int tb_abs = mt * 8 + 2 * ms + s;
    const int b  = tb_abs >> 7;
    const int tb = tb_abs & 127;
    const int hs = tt >> 1;
    const int e  = (lc & 3) + 4 * (tt & 1);
    #pragma unroll
    for (int r = 0; r < 4; ++r) {
      const int lane_c = 4 * lg + r + 16 * (lc >> 2);
      // q
      {
        const float val = acc[0][s][r];
        const u16 hvv = f2bu(val);
        u16* dst = qpk + (((size_t)(b * 128 + tb) * 4 + hs) * 2 * 64 + lane_c) * 8 + e;
        dst[0]   = hvv;
        dst[512] = f2bu(val - bu2f(hvv));
      }
      // k
      {
        const float val = acc[1][s][r];
        const u16 hvv = f2bu(val);
        u16* dst = kpk + (((size_t)(b * 128 + tb) * 4 + hs) * 2 * 64 + lane_c) * 8 + e;
        dst[0]   = hvv;
        dst[512] = f2bu(val - bu2f(hvv));
      }
      // v
      {
        const int kt = tb >> 1;
        const int lane_cv = lc + 16 * lg;
        const int ev = r + 4 * (tb & 1);
        vpk[(((size_t)(b * 64 + kt) * 8 + tt) * 64 + lane_cv) * 8 + ev] = f2bu(acc[2][s][r]);
      }
    }
  }
}

// ---------------------------------------------------------------------------
// Kernel 2: causal flash attention (round-4 structure + setprio on MFMA
// clusters). 8 waves, intra-block split-K (kb = w mod 8), 1 q-tile/wave.
// Swapped QK^T so P lands in PV's A-operand layout. LDS combine (bf16).
// ---------------------------------------------------------------------------
__global__ __launch_bounds__(512, 4) void attn_kernel(
    const u16* __restrict__ qpk, const u16* __restrict__ kpk,
    const u16* __restrict__ vpk, float* __restrict__ out) {
  __shared__ float lm[8][16];
  __shared__ float ll[8][16];
  __shared__ u16 lo[8][16][132];     // bf16 partial O

  const int bid = blockIdx.x;
  const int b   = bid & 7;           // batch -> XCD affinity
  const int qt  = bid >> 3;          // 0..127
  const int w    = threadIdx.x >> 6;
  const int lane = threadIdx.x & 63;
  const int lg = lane >> 4, lc = lane & 15;

  // Q fragments: [b][qt][hs][hl][lane][8], tile stride 4096 u16
  Frag bqh[4], bql[4];
  const u16* qp = qpk + (size_t)(b * 128 + qt) * 4096 + lane * 8;
  #pragma unroll
  for (int hs = 0; hs < 4; ++hs) {
    bqh[hs].u4 = *(const u32x4*)(qp + (size_t)(hs * 2 + 0) * 512);
    bql[hs].u4 = *(const u32x4*)(qp + (size_t)(hs * 2 + 1) * 512);
  }

  f32x4 zero = {0.f, 0.f, 0.f, 0.f};
  f32x4 o_acc[8];
  #pragma unroll
  for (int i = 0; i < 8; ++i) o_acc[i] = zero;
  float m_run = -INFINITY, l_run = 0.f;

  const int myq = qt * 16 + lc;
  const int nkb = qt >> 2;           // last 64-wide k-block

  for (int kb = w; kb <= nkb; kb += 8) {
    f32x4 s[4];
    #pragma unroll
    for (int t = 0; t < 4; ++t) s[t] = zero;

    const u16* kp = kpk + (size_t)(b * 128 + kb * 4) * 4096 + lane * 8;
    __builtin_amdgcn_s_setprio(1);
    #pragma unroll
    for (int t = 0; t < 4; ++t) {
      #pragma unroll
      for (int hs = 0; hs < 4; ++hs) {
        const u16* p = kp + (size_t)(t * 8 + hs * 2) * 512;
        Frag akh, akl;
        akh.u4 = *(const u32x4*)p;
        akl.u4 = *(const u32x4*)(p + 512);
        s[t] = MFMA(akh.v, bqh[hs].v, s[t]);
        s[t] = MFMA(akh.v, bql[hs].v, s[t]);
        s[t] = MFMA(akl.v, bqh[hs].v, s[t]);
      }
    }
    __builtin_amdgcn_s_setprio(0);

    // scale by sqrt(C)=32; causal + (tril==0 -> -inf) semantics
    float pmax = -INFINITY;
    #pragma unroll
    for (int t = 0; t < 4; ++t) {
      #pragma unroll
      for (int r = 0; r < 4; ++r) {
        const int kk = kb * 64 + t * 16 + 4 * lg + r;
        float v = s[t][r] * 32.0f;
        if (kk > myq || v == 0.0f) v = -INFINITY;
        s[t][r] = v;
        pmax = fmaxf(pmax, v);
      }
    }
    pmax = fmaxf(pmax, __shfl_xor(pmax, 16));
    pmax = fmaxf(pmax, __shfl_xor(pmax, 32));
    const float m_new = fmaxf(m_run, pmax);
    const float alpha = __expf(m_run - m_new);

    float sum = 0.f;
    u16 pb[16];
    #pragma unroll
    for (int t = 0; t < 4; ++t) {
      #pragma unroll
      for (int r = 0; r < 4; ++r) {
        const float p = __expf(s[t][r] - m_new);
        sum += p;
        pb[t * 4 + r] = f2bu(p);
      }
    }
    sum += __shfl_xor(sum, 16);
    sum += __shfl_xor(sum, 32);
    l_run = l_run * alpha + sum;
    m_run = m_new;

    float al[4];
    #pragma unroll
    for (int r = 0; r < 4; ++r) al[r] = __shfl(alpha, 4 * lg + r);
    #pragma unroll
    for (int i = 0; i < 8; ++i) {
      #pragma unroll
      for (int r = 0; r < 4; ++r) o_acc[i][r] *= al[r];
    }

    Frag pa[2];
    #pragma unroll
    for (int ks = 0; ks < 2; ++ks) {
      #pragma unroll
      for (int e = 0; e < 8; ++e)
        pa[ks].s[e] = pb[(2 * ks + (e >> 2)) * 4 + (e & 3)];
    }

    __builtin_amdgcn_s_setprio(1);
    #pragma unroll
    for (int ks = 0; ks < 2; ++ks) {
      const u16* vp = vpk + (size_t)(b * 64 + kb * 2 + ks) * 4096 + lane * 8;
      #pragma unroll
      for (int ht = 0; ht < 8; ++ht) {
        Frag bv;
        bv.u4 = *(const u32x4*)(vp + (size_t)ht * 512);
        o_acc[ht] = MFMA(pa[ks].v, bv.v, o_acc[ht]);
      }
    }
    __builtin_amdgcn_s_setprio(0);
  }

  // --- combine 8 partials through LDS ---
  if (lane < 16) { lm[w][lane] = m_run; ll[w][lane] = l_run; }
  #pragma unroll
  for (int ht = 0; ht < 8; ++ht)
    #pragma unroll
    for (int r = 0; r < 4; ++r)
      lo[w][4 * lg + r][ht * 16 + lc] = f2bu(o_acc[ht][r]);
  __syncthreads();

  const int tid = threadIdx.x;
  const int q  = tid >> 5;            // 0..15
  const int hb = (tid & 31) * 4;      // 0..124
  float M = -INFINITY;
  #pragma unroll
  for (int ww = 0; ww < 8; ++ww) M = fmaxf(M, lm[ww][q]);
  float lsum = 0.f;
  f32x4 osum = {0.f, 0.f, 0.f, 0.f};
  #pragma unroll
  for (int ww = 0; ww < 8; ++ww) {
    const float sc = __expf(lm[ww][q] - M);
    lsum += sc * ll[ww][q];
    const u16x4 ov = *(const u16x4*)&lo[ww][q][hb];
    #pragma unroll
    for (int j = 0; j < 4; ++j) osum[j] += sc * bu2f(ov[j]);
  }
  const float inv = 1.0f / lsum;
  f32x4 res = {osum[0] * inv, osum[1] * inv, osum[2] * inv, osum[3] * inv};
  *(f32x4*)&out[((size_t)(b * T + qt * 16 + q)) * H + hb] = res;
}

// ---------------------------------------------------------------------------
extern "C" void kernel_launch(void* const* d_in, const int* in_sizes, int n_in,
                              void* d_out, int out_size, void* d_ws, size_t ws_size,
                              hipStream_t stream) {
  (void)in_sizes; (void)n_in; (void)out_size; (void)ws_size;
  const float* x  = (const float*)d_in[0];
  const float* Wk = (const float*)d_in[1];
  const float* Wq = (const float*)d_in[2];
  const float* Wv = (const float*)d_in[3];
  float* out = (float*)d_out;

  u16* w = (u16*)d_ws;
  const size_t WPQK = (size_t)8 * 32 * 2 * 64 * 8;       // 262144
  const size_t WPV  = (size_t)8 * 32 * 64 * 8;           // 131072
  const size_t QKP  = (size_t)NB * 128 * 4 * 2 * 64 * 8; // 4194304
  u16* wpq = w;
  u16* wpk = wpq + WPQK;
  u16* wpv = wpk + WPQK;
  u16* qpk = wpv + WPV;
  u16* kpk = qpk + QKP;
  u16* vpk = kpk + QKP;

  prep_w<<<192, 256, 0, stream>>>(Wk, Wq, Wv, wpq, wpk, wpv);
  proj_kernel<<<512, 512, 0, stream>>>(x, wpq, wpk, wpv, qpk, kpk, vpk);
  attn_kernel<<<NB * (T / 16), 512, 0, stream>>>(qpk, kpk, vpk, out);
}